// Round 1
// 2011.386 us; speedup vs baseline: 2.0569x; 2.0569x over previous
//
#include <hip/hip_runtime.h>
#include <math.h>

#define VOCAB  50257
#define EMBED  256
#define NHEAD  8
#define HEAD   32
#define TLEN   512
#define BATCH  4
#define ROWS   (BATCH*TLEN)     /* 2048 */
#define HIDDEN 1024
#define LOGN   ((size_t)ROWS * (size_t)VOCAB)
#define SCALE  0.0625f          /* EMBED^-0.5 = 1/16 */
#define NPAD   50304            /* 393 * 128 */

/* ---------------- helpers ---------------- */
__device__ __forceinline__ unsigned short f2bf(float f) {
    unsigned u = __builtin_bit_cast(unsigned, f);
    u += 0x7fffu + ((u >> 16) & 1u);          /* RNE */
    return (unsigned short)(u >> 16);
}

__device__ __forceinline__ void gll16(const void* g, void* l) {
    __builtin_amdgcn_global_load_lds(
        (const __attribute__((address_space(1))) void*)g,
        (__attribute__((address_space(3))) void*)l, 16, 0, 0);
}

typedef __attribute__((ext_vector_type(8))) short bf16x8;
typedef __attribute__((ext_vector_type(4))) float f32x4;

/* ---------------- K1: x = tok_emb[idx] + pos_emb[t] ---------------- */
__global__ void k_embed(const int* __restrict__ idx, const float* __restrict__ tok,
                        const float* __restrict__ pos, float* __restrict__ x) {
    int r = blockIdx.x, e = threadIdx.x;
    x[r*EMBED + e] = tok[(size_t)idx[r]*EMBED + e] + pos[(r & (TLEN-1))*EMBED + e];
}

/* ---------------- K2: q/k/v[n][r][h] = x[r,:] @ W[n,:,h] ------------ */
__global__ void k_qkv(const float* __restrict__ x,  const float* __restrict__ Wq,
                      const float* __restrict__ Wk, const float* __restrict__ Wv,
                      float* __restrict__ q, float* __restrict__ k, float* __restrict__ v) {
    __shared__ float xs[EMBED];
    int r = blockIdx.x, tid = threadIdx.x;
    xs[tid] = x[r*EMBED + tid];
    __syncthreads();
    int n = tid >> 5, h = tid & 31;
    const float* wq = Wq + n*EMBED*HEAD + h;
    const float* wk = Wk + n*EMBED*HEAD + h;
    const float* wv = Wv + n*EMBED*HEAD + h;
    float aq = 0.f, ak = 0.f, av = 0.f;
    for (int e = 0; e < EMBED; e++) {
        float xv = xs[e];
        aq += xv * wq[e*HEAD];
        ak += xv * wk[e*HEAD];
        av += xv * wv[e*HEAD];
    }
    int o = (n*ROWS + r)*HEAD + h;
    q[o] = aq; k[o] = ak; v[o] = av;
}

/* ------- K3a: per (n,b) column stats of softmax over QUERY axis ------- */
__global__ void k_colstats(const float* __restrict__ q, const float* __restrict__ k,
                           float* __restrict__ colM, float* __restrict__ colRL) {
    __shared__ float qs[HEAD][TLEN];           /* 64 KB */
    int nb = blockIdx.x;                       /* nb = n*4 + b */
    const float* qb = q + nb*TLEN*HEAD;
    const float* kb = k + nb*TLEN*HEAD;
    for (int i = threadIdx.x; i < TLEN*HEAD; i += 512)
        qs[i & 31][i >> 5] = qb[i];
    __syncthreads();
    int s = threadIdx.x;                       /* 512 threads: one column each */
    float kreg[HEAD];
#pragma unroll
    for (int h = 0; h < HEAD; h++) kreg[h] = kb[s*HEAD + h];
    float m = -1e30f, l = 0.f;
    for (int t = s; t < TLEN; t++) {
        float sc = 0.f;
#pragma unroll
        for (int h = 0; h < HEAD; h++) sc += qs[h][t] * kreg[h];
        sc *= SCALE;
        float nm = fmaxf(m, sc);
        l = l * __expf(m - nm) + __expf(sc - nm);
        m = nm;
    }
    colM[nb*TLEN + s]  = m;
    colRL[nb*TLEN + s] = 1.0f / l;
}

/* ------- K3b: out[t,:] = sum_{s<=t} exp(sc(t,s)-M[s])*RL[s] * v[s,:] --- */
__global__ void k_attnout(const float* __restrict__ q, const float* __restrict__ k,
                          const float* __restrict__ v, const float* __restrict__ colM,
                          const float* __restrict__ colRL, float* __restrict__ outc) {
    __shared__ float ks[256][HEAD];            /* 32 KB */
    __shared__ float vs[256][HEAD];            /* 32 KB */
    int nb = blockIdx.x;
    int n = nb >> 2, b = nb & 3;
    int base = nb*TLEN*HEAD;
    int t = threadIdx.x;
    int nbT = nb*TLEN;
    float qr[HEAD], acc[HEAD];
#pragma unroll
    for (int h = 0; h < HEAD; h++) { qr[h] = q[base + t*HEAD + h]; acc[h] = 0.f; }
    for (int c0 = 0; c0 < TLEN; c0 += 256) {
        __syncthreads();
        for (int i = threadIdx.x; i < 256*HEAD; i += 512) {
            ks[i >> 5][i & 31] = k[base + c0*HEAD + i];
            vs[i >> 5][i & 31] = v[base + c0*HEAD + i];
        }
        __syncthreads();
        int send = t < c0 + 255 ? t : c0 + 255;
        for (int s = c0; s <= send; s++) {
            float sc = 0.f;
#pragma unroll
            for (int h = 0; h < HEAD; h++) sc += qr[h] * ks[s - c0][h];
            float w = __expf(sc * SCALE - colM[nbT + s]) * colRL[nbT + s];
#pragma unroll
            for (int h = 0; h < HEAD; h++) acc[h] += w * vs[s - c0][h];
        }
    }
    int r = b*TLEN + t;
#pragma unroll
    for (int h = 0; h < HEAD; h++) outc[r*EMBED + n*HEAD + h] = acc[h];
}

/* ---------------- K4: h = relu(outc @ W1 + b1) -> bf16, 8 rows/block -- */
__global__ void k_mlp(const float* __restrict__ outc, const float* __restrict__ W1,
                      const float* __restrict__ b1, unsigned short* __restrict__ hb16) {
    __shared__ float xs[8][EMBED];             /* 8 KB */
    int r0 = blockIdx.x * 8, tid = threadIdx.x;
    for (int i = tid; i < 8*EMBED; i += 256) xs[i >> 8][i & 255] = outc[r0*EMBED + i];
    __syncthreads();
    int j0 = tid * 4;
    float acc[8][4];
#pragma unroll
    for (int i = 0; i < 8; i++)
#pragma unroll
        for (int c = 0; c < 4; c++) acc[i][c] = 0.f;
    for (int e = 0; e < EMBED; e++) {
        float4 w = *(const float4*)(W1 + e*HIDDEN + j0);
#pragma unroll
        for (int i = 0; i < 8; i++) {
            float xv = xs[i][e];
            acc[i][0] += xv * w.x; acc[i][1] += xv * w.y;
            acc[i][2] += xv * w.z; acc[i][3] += xv * w.w;
        }
    }
    float4 bb = *(const float4*)(b1 + j0);
#pragma unroll
    for (int i = 0; i < 8; i++) {
        ushort4 o;
        o.x = f2bf(fmaxf(acc[i][0] + bb.x, 0.f));
        o.y = f2bf(fmaxf(acc[i][1] + bb.y, 0.f));
        o.z = f2bf(fmaxf(acc[i][2] + bb.z, 0.f));
        o.w = f2bf(fmaxf(acc[i][3] + bb.w, 0.f));
        *(ushort4*)(hb16 + (size_t)(r0 + i)*HIDDEN + j0) = o;
    }
}

/* -------- K4b: w2t[n][k] = bf16(W2[k][n]), zero-padded to NPAD rows --- */
__global__ void k_w2t(const float* __restrict__ W2, unsigned short* __restrict__ w2t) {
    __shared__ float s[64][65];
    int n0 = blockIdx.x * 64, k0 = blockIdx.y * 64;
    int tid = threadIdx.x;
#pragma unroll
    for (int i = 0; i < 16; i++) {
        int idx = tid + i*256;
        int kr = idx >> 6, nc = idx & 63;
        int n = n0 + nc;
        s[kr][nc] = (n < VOCAB) ? W2[(size_t)(k0 + kr)*VOCAB + n] : 0.f;
    }
    __syncthreads();
#pragma unroll
    for (int i = 0; i < 8; i++) {
        int idx = tid + i*256;
        int nr = idx >> 5, cp = (idx & 31) * 2;
        ushort2 o;
        o.x = f2bf(s[cp + 0][nr]);
        o.y = f2bf(s[cp + 1][nr]);
        *(ushort2*)(w2t + (size_t)(n0 + nr)*HIDDEN + k0 + cp) = o;
    }
}

/* ---------------- K5: logits = h @ W2 + b2  (bf16 MFMA) ----------------
   m97 structure: 128x128 tile, BK=32, 4 waves (2x2), 4x4 16x16x32 mfma
   per wave, global_load_lds width-16 staging, 2 barriers/K-step.
   Grid: bm fastest (16) so consecutive blocks share the B panel in L2. */
__global__ __launch_bounds__(256) void k_lmhead_mfma(
        const unsigned short* __restrict__ hb16,
        const unsigned short* __restrict__ w2t,
        const float* __restrict__ b2, float* __restrict__ logits) {
    __shared__ unsigned short As[128*32];      /* 8 KB */
    __shared__ unsigned short Bs[128*32];      /* 8 KB */
    int bid = blockIdx.x;
    int bm = bid & 15, bn = bid >> 4;
    int r0 = bm << 7, n0 = bn << 7;
    int tid = threadIdx.x;
    int lane = tid & 63;
    int wv = tid >> 6;
    int wm = (wv >> 1) << 6, wn = (wv & 1) << 6;
    int lr = lane & 15;                        /* frag row (A) / col (B,C) */
    int hi = lane >> 4;                        /* k-block 0..3 */
    int koff = hi << 3;

    f32x4 acc[4][4];
#pragma unroll
    for (int m = 0; m < 4; m++)
#pragma unroll
        for (int n = 0; n < 4; n++) acc[m][n] = (f32x4){0.f, 0.f, 0.f, 0.f};

    for (int k0 = 0; k0 < HIDDEN; k0 += 32) {
        __syncthreads();                       /* prev-tile reads done */
#pragma unroll
        for (int j = 0; j < 2; j++) {
            int idx = (j << 8) + tid;          /* 0..511 */
            int row = idx >> 2, kk = (idx & 3) << 3;
            gll16(hb16 + (size_t)(r0 + row)*HIDDEN + k0 + kk, As + idx*8);
            gll16(w2t  + (size_t)(n0 + row)*HIDDEN + k0 + kk, Bs + idx*8);
        }
        __syncthreads();                       /* vmcnt drained -> LDS ready */
        bf16x8 af[4], bfr[4];
#pragma unroll
        for (int m = 0; m < 4; m++)
            af[m] = *(const bf16x8*)(As + (wm + m*16 + lr)*32 + koff);
#pragma unroll
        for (int n = 0; n < 4; n++)
            bfr[n] = *(const bf16x8*)(Bs + (wn + n*16 + lr)*32 + koff);
#pragma unroll
        for (int m = 0; m < 4; m++)
#pragma unroll
            for (int n = 0; n < 4; n++)
                acc[m][n] = __builtin_amdgcn_mfma_f32_16x16x32_bf16(
                    af[m], bfr[n], acc[m][n], 0, 0, 0);
    }

    int rbase = r0 + wm + (hi << 2);
#pragma unroll
    for (int n = 0; n < 4; n++) {
        int col = n0 + wn + n*16 + lr;
        if (col >= VOCAB) continue;
        float bias = b2[col];
#pragma unroll
        for (int m = 0; m < 4; m++) {
            float* out = logits + (size_t)(rbase + m*16) * VOCAB + col;
#pragma unroll
            for (int j = 0; j < 4; j++)
                out[(size_t)j * VOCAB] = acc[m][n][j] + bias;
        }
    }
}

/* -------- K6: per-row online logsumexp + per-row NLL ------------------ */
__global__ void k_rowstats(const float* __restrict__ logits, const int* __restrict__ tgt,
                           float* __restrict__ rowM, float* __restrict__ rowRL,
                           float* __restrict__ nll) {
    __shared__ float sm[256], sl[256];
    int r = blockIdx.x, tid = threadIdx.x;
    const float* row = logits + (size_t)r * VOCAB;
    float m = -1e30f, l = 0.f;
    for (int i = tid; i < VOCAB; i += 256) {
        float xv = row[i];
        float nm = fmaxf(m, xv);
        l = l * __expf(m - nm) + __expf(xv - nm);
        m = nm;
    }
    sm[tid] = m; sl[tid] = l;
    __syncthreads();
    for (int off = 128; off > 0; off >>= 1) {
        if (tid < off) {
            float m2 = sm[tid + off], l2 = sl[tid + off];
            float nm = fmaxf(sm[tid], m2);
            sl[tid] = sl[tid] * __expf(sm[tid] - nm) + l2 * __expf(m2 - nm);
            sm[tid] = nm;
        }
        __syncthreads();
    }
    if (tid == 0) {
        float M = sm[0], L = sl[0];
        rowM[r] = M;
        rowRL[r] = 1.0f / L;
        nll[r] = (M + logf(L)) - row[tgt[r]];
    }
}

/* -------- K7: loss = mean(nll) ---------------------------------------- */
__global__ void k_loss(const float* __restrict__ nll, float* __restrict__ out_loss) {
    __shared__ float s[256];
    int tid = threadIdx.x;
    float a = 0.f;
    for (int i = tid; i < ROWS; i += 256) a += nll[i];
    s[tid] = a;
    __syncthreads();
    for (int off = 128; off > 0; off >>= 1) {
        if (tid < off) s[tid] += s[tid + off];
        __syncthreads();
    }
    if (tid == 0) out_loss[0] = s[0] / (float)ROWS;
}

/* -------- K8: o_prob = exp(logits - M) * RL --------------------------- */
__global__ void k_probs(const float* __restrict__ logits, const float* __restrict__ rowM,
                        const float* __restrict__ rowRL, float* __restrict__ oprob) {
    int r = blockIdx.x, tid = threadIdx.x;
    size_t base = (size_t)r * VOCAB;
    float M = rowM[r], RL = rowRL[r];
    int head = (4 - (r & 3)) & 3;
    for (int i = tid; i < head; i += 256)
        oprob[base + i] = __expf(logits[base + i] - M) * RL;
    int nvec = (VOCAB - head) >> 2;
    const float4* in4 = (const float4*)(logits + base + head);
    float4* out4 = (float4*)(oprob + base + head);
    for (int i = tid; i < nvec; i += 256) {
        float4 xv = in4[i];
        float4 o;
        o.x = __expf(xv.x - M) * RL;
        o.y = __expf(xv.y - M) * RL;
        o.z = __expf(xv.z - M) * RL;
        o.w = __expf(xv.w - M) * RL;
        out4[i] = o;
    }
    for (int i = head + nvec*4 + tid; i < VOCAB; i += 256)
        oprob[base + i] = __expf(logits[base + i] - M) * RL;
}

extern "C" void kernel_launch(void* const* d_in, const int* in_sizes, int n_in,
                              void* d_out, int out_size, void* d_ws, size_t ws_size,
                              hipStream_t stream) {
    const int*   idx = (const int*)d_in[0];
    const int*   tgt = (const int*)d_in[1];
    const float* tok = (const float*)d_in[2];
    const float* pos = (const float*)d_in[3];
    const float* Wq  = (const float*)d_in[4];
    const float* Wk  = (const float*)d_in[5];
    const float* Wv  = (const float*)d_in[6];
    const float* W1  = (const float*)d_in[7];
    const float* b1  = (const float*)d_in[8];
    const float* W2  = (const float*)d_in[9];
    const float* b2  = (const float*)d_in[10];

    float* logits = (float*)d_out;
    float* loss   = logits + LOGN;
    float* oprob  = logits + LOGN + 1;

    /* bf16 W2^T scratch lives in the (not-yet-written) o_prob region:
       NPAD*HIDDEN*2B = 103 MB << 411 MB, aligned up to 256B. o_prob is
       fully overwritten by k_probs afterwards. */
    unsigned short* w2t = (unsigned short*)(((uintptr_t)(void*)oprob + 255) & ~(uintptr_t)255);

    /* workspace layout (floats) */
    float* ws    = (float*)d_ws;
    float* x     = ws;                     /* 524288  */
    float* q     = x     + 524288;         /* 524288  */
    float* k     = q     + 524288;
    float* v     = k     + 524288;
    float* colM  = v     + 524288;         /* 16384   */
    float* colRL = colM  + 16384;          /* 16384   */
    float* att   = colRL + 16384;          /* 524288  */
    float* hbF   = att   + 524288;         /* 1048576 floats = 2048*1024 bf16 */
    unsigned short* hb16 = (unsigned short*)hbF;
    float* rowM  = hbF   + 1048576;        /* 2048    */
    float* rowRL = rowM  + 2048;
    float* nll   = rowRL + 2048;

    k_embed   <<<ROWS, EMBED, 0, stream>>>(idx, tok, pos, x);
    k_w2t     <<<dim3(NPAD/64, HIDDEN/64), 256, 0, stream>>>(W2, w2t);
    k_qkv     <<<ROWS, 256,   0, stream>>>(x, Wq, Wk, Wv, q, k, v);
    k_colstats<<<NHEAD*BATCH, TLEN, 0, stream>>>(q, k, colM, colRL);
    k_attnout <<<NHEAD*BATCH, TLEN, 0, stream>>>(q, k, v, colM, colRL, att);
    k_mlp     <<<ROWS/8, 256, 0, stream>>>(att, W1, b1, hb16);
    /* 16 m-tiles x 393 n-tiles */
    k_lmhead_mfma<<<16 * (NPAD/128), 256, 0, stream>>>(hb16, w2t, b2, logits);
    k_rowstats<<<ROWS, 256, 0, stream>>>(logits, tgt, rowM, rowRL, nll);
    k_loss    <<<1, 256, 0, stream>>>(nll, loss);
    k_probs   <<<ROWS, 256, 0, stream>>>(logits, rowM, rowRL, oprob);
}